// Round 18
// baseline (127.397 us; speedup 1.0000x reference)
//
#include <hip/hip_runtime.h>
#include <stdint.h>
#include <stddef.h>

// Attention_50886772523162: x[2,2048,1024] -> causal MHA (16 heads, hd=64) -> out
// dtype (fp32 vs bf16) detected inline (deterministic wave-local sample of x);
// compute bf16 MFMA, fp32 accum.
// Pipeline (4 launches): prep (convert x + transpose weights, fused) ->
//           QKV proj (one GEMM) -> flash attn (R12-verified, frozen) -> O proj.
// NOTE: permlane32_swap is BLACKLISTED: raw asm (R5) -> NaN; builtin (R17) ->
//       wrong lane movement (absmax 2.89). Cross-half transport stays on the
//       verified __shfl_xor(...,32) path.
// NOTE: R8: causal imbalance => complementary strips (P, 63-P).
// NOTE: R9-R14 ledger: every TLP scheme and dual-strip ILP lost to overhead;
//       attn structurally ~75 us in this 2-wave structure — frozen since R12.
// R16 (verified 127.3 us): GEMM 32x32x16 (half the MFMA instructions).

typedef __bf16 bf16;
typedef __bf16 bf16x8 __attribute__((ext_vector_type(8)));
typedef __bf16 bf16x4 __attribute__((ext_vector_type(4)));
typedef __bf16 bf16x2 __attribute__((ext_vector_type(2)));
typedef float  f32x4  __attribute__((ext_vector_type(4)));
typedef float  f32x16 __attribute__((ext_vector_type(16)));

#define NSEQ 2048
#define DM   1024
#define HD   64
#define QKVS 3072          // fused QKV row stride
#define LOG2E 1.44269504f

#define GLD16(g, l) __builtin_amdgcn_global_load_lds(                         \
    (const __attribute__((address_space(1))) void*)(g),                       \
    (__attribute__((address_space(3))) void*)(l), 16, 0, 0)

// ---------------- inline dtype detection ----------------
// Every wave samples the SAME first 1024 words of x (L1-hot): low-16-bit
// exponent of a bf16-packed N(0,1) sample is in [110,132] essentially always;
// for fp32 those are uniform mantissa bits (~9% hit rate).
static __device__ __forceinline__ int detect_bf16(const uint32_t* __restrict__ x) {
  const int lane = threadIdx.x & 63;
  int cc = 0;
#pragma unroll
  for (int k = 0; k < 16; ++k) {
    const uint32_t e = (x[lane * 16 + k] >> 7) & 0xFF;
    if (e >= 110 && e <= 132) cc++;
  }
#pragma unroll
  for (int off = 1; off < 64; off <<= 1) cc += __shfl_xor(cc, off);
  return cc > 512;   // of 1024 samples
}

// ---------------- fused prep: convert x + transpose(+convert) weights --------
// grid.x = 6144 blocks of 256 threads:
//   [0,2048)     : x -> xb (bf16), 2048 elems/block
//   [2048,3072)  : Wq  [1024][1024] -> WqkvT rows [0,1024)
//   [3072,5120)  : Wkv [1024][2048] -> WqkvT rows [1024,3072)
//   [5120,6144)  : Wo  [1024][1024] -> WoT
__global__ __launch_bounds__(256) void prep(
    const void* __restrict__ x, const void* __restrict__ Wq,
    const void* __restrict__ Wkv, const void* __restrict__ Wo,
    bf16* __restrict__ xb, bf16* __restrict__ WqkvT, bf16* __restrict__ WoT)
{
  const int flag = detect_bf16((const uint32_t*)x);
  const int b = blockIdx.x, tid = threadIdx.x;

  if (b < 2048) {                      // ---- convert x ----
    const int i = (b * 256 + tid) * 8;
    if (flag) {
      *(bf16x8*)(xb + i) = *(const bf16x8*)((const bf16*)x + i);
    } else {
      const float* f = (const float*)x;
      bf16x8 v;
#pragma unroll
      for (int e = 0; e < 8; ++e) v[e] = (bf16)f[i + e];
      *(bf16x8*)(xb + i) = v;
    }
    return;                            // block-uniform exit (no barrier below)
  }

  // ---- weight transpose(+convert): in[K][N] -> out[N][K] ----
  __shared__ bf16 tile[32][33];
  const void* in;
  bf16* out;
  int K, N, idx;
  if (b < 3072)      { in = Wq;  out = WqkvT;               K = 1024; N = 1024; idx = b - 2048; }
  else if (b < 5120) { in = Wkv; out = WqkvT + 1024 * 1024; K = 1024; N = 2048; idx = b - 3072; }
  else               { in = Wo;  out = WoT;                 K = 1024; N = 1024; idx = b - 5120; }
  const int ntiles_n = N / 32;
  const int n0 = (idx % ntiles_n) * 32, k0 = (idx / ntiles_n) * 32;
  const int tx = tid & 31, ty = tid >> 5;    // 32 x 8

  if (flag) {
    const bf16* p = (const bf16*)in;
#pragma unroll
    for (int i = ty; i < 32; i += 8)
      tile[i][tx] = p[(size_t)(k0 + i) * N + n0 + tx];
  } else {
    const float* p = (const float*)in;
#pragma unroll
    for (int i = ty; i < 32; i += 8)
      tile[i][tx] = (bf16)p[(size_t)(k0 + i) * N + n0 + tx];
  }
  __syncthreads();
#pragma unroll
  for (int i = ty; i < 32; i += 8)
    out[(size_t)(n0 + i) * K + k0 + tx] = tile[tx][i];
}

// ---------------- GEMM: C[M][N] = A[M][K] * Bt[N][K]^T ----------------
// 128x128 tile, BK=64, 4 waves (2x2, each 64x64), mfma_f32_32x32x16_bf16.
// Staging via global_load_lds (16B/lane, linear LDS dest, pre-swizzled source).
// Fragment patterns attn-verified: A/B operand row = lane&31,
// k = ks*16 + (lane>>5)*8 + e; read offset (ks*32+h*16) ^ ((row&7)<<4).
// D layout: col = B-row = lane&31, row(r) = (r&3) + 8*(r>>2) + 4*h.
// xdet: nullptr -> bf16 output; else inline-detect x's dtype for the output.
__global__ __launch_bounds__(256) void gemm_bt(
    const bf16* __restrict__ A, const bf16* __restrict__ Bt,
    void* __restrict__ C, int M, int N, int K, const uint32_t* xdet)
{
  __shared__ bf16 As[128][64];
  __shared__ bf16 Bs[128][64];
  const int tid  = threadIdx.x;
  const int wave = tid >> 6, lane = tid & 63;
  const int c = lane & 31, h = lane >> 5;
  const int m0 = blockIdx.y * 128, n0 = blockIdx.x * 128;
  const int wr = (wave >> 1) * 64, wc = (wave & 1) * 64;
  const int lrow = lane >> 3;                    // row within 8-row chunk
  const int lcol = 8 * ((lane & 7) ^ lrow);      // pre-swizzled source col (elems)

  f32x16 acc[2][2] = {};

  for (int kt = 0; kt < K; kt += 64) {
    __syncthreads();                              // protect prev-iter reads
#pragma unroll
    for (int p = 0; p < 4; ++p) {
      const int chunk = wave * 4 + p;             // 8 rows per chunk
      const int r = chunk * 8 + lrow;
      GLD16(A  + (size_t)(m0 + r) * K + kt + lcol, &As[chunk * 8][0]);
      GLD16(Bt + (size_t)(n0 + r) * K + kt + lcol, &Bs[chunk * 8][0]);
    }
    __syncthreads();                              // vmcnt(0) drain + barrier
#pragma unroll
    for (int ks = 0; ks < 4; ++ks) {
      bf16x8 af[2], bfv[2];
#pragma unroll
      for (int mb = 0; mb < 2; ++mb) {
        const int ar = wr + mb * 32 + c;
        af[mb]  = *(const bf16x8*)((const char*)&As[ar][0] +
                   ((ks * 32 + h * 16) ^ ((ar & 7) << 4)));
        const int br = wc + mb * 32 + c;
        bfv[mb] = *(const bf16x8*)((const char*)&Bs[br][0] +
                   ((ks * 32 + h * 16) ^ ((br & 7) << 4)));
      }
#pragma unroll
      for (int mb = 0; mb < 2; ++mb)
#pragma unroll
        for (int nb = 0; nb < 2; ++nb)
          acc[mb][nb] = __builtin_amdgcn_mfma_f32_32x32x16_bf16(
              af[mb], bfv[nb], acc[mb][nb], 0, 0, 0);
    }
  }
  // D: col = n0+wc+nb*32+c ; row = m0+wr+mb*32 + (r&3)+8*(r>>2)+4*h
  const int as_bf16 = xdet ? detect_bf16(xdet) : 1;
  const int ccol = n0 + wc + c;
  if (as_bf16) {
    bf16* Cb = (bf16*)C;
#pragma unroll
    for (int mb = 0; mb < 2; ++mb)
#pragma unroll
      for (int nb = 0; nb < 2; ++nb)
#pragma unroll
        for (int r = 0; r < 16; ++r) {
          const int row = m0 + wr + mb * 32 + (r & 3) + 8 * (r >> 2) + 4 * h;
          Cb[(size_t)row * N + ccol + nb * 32] = (bf16)acc[mb][nb][r];
        }
  } else {
    float* Cf = (float*)C;
#pragma unroll
    for (int mb = 0; mb < 2; ++mb)
#pragma unroll
      for (int nb = 0; nb < 2; ++nb)
#pragma unroll
        for (int r = 0; r < 16; ++r) {
          const int row = m0 + wr + mb * 32 + (r & 3) + 8 * (r >> 2) + 4 * h;
          Cf[(size_t)row * N + ccol + nb * 32] = acc[mb][nb][r];
        }
  }
}

// ---------------- causal flash attention (R12-verified, frozen) ----------------
// QKV: [B*N][3072] rows = (Q | K | V), head col offset hi*64.
// Block = 2 waves (128 threads); grid 16 pairs x 32 bh = 512 blocks.
// Wave owns strips sA = 2*pair+wave and sB = 63-sA (32 q-rows each).
// K/V MFMA fragments are strip-independent -> loaded ONCE per tile and shared.
static __device__ inline uint32_t pk2(float a, float b) {
  bf16x2 t; t[0] = (bf16)a; t[1] = (bf16)b;
  return __builtin_bit_cast(uint32_t, t);
}

// One strip x one KV tile using pre-loaded K/V fragments.
static __device__ __forceinline__ void strip_compute(
    const bf16x8 (&kf)[2][4], const bf16x8 (&vf)[2][2][2],
    const bf16x8 (&qf)[4], f32x16 (&oacc)[2], float& m, float& l,
    const int j0, const int q0, const int c, const int h)
{
  const int qrow = q0 + c;
  const int blkmax = (j0 + 32 <= q0 + 31) ? 2 : 1;

  f32x16 sv[2];
  __builtin_amdgcn_s_setprio(1);
#pragma unroll
  for (int blk = 0; blk < 2; ++blk)
    if (blk < blkmax) {
      f32x16 a = {};
#pragma unroll
      for (int ks = 0; ks < 4; ++ks)
        a = __builtin_amdgcn_mfma_f32_32x32x16_bf16(kf[blk][ks], qf[ks], a, 0, 0, 0);
      sv[blk] = a;
    }
  __builtin_amdgcn_s_setprio(0);

  if (j0 + 63 > q0) {                       // causal mask (raw-S domain)
#pragma unroll
    for (int blk = 0; blk < 2; ++blk)
      if (blk < blkmax) {
        const int kvb = j0 + blk * 32 + 4 * h;
#pragma unroll
        for (int r = 0; r < 16; ++r) {
          const int kv = kvb + (r & 3) + 8 * (r >> 2);
          if (kv > qrow) sv[blk][r] = -4.0e8f;
        }
      }
  }

  // online softmax, lane-local; defer-max (T13, THR=8); tree reductions
  float red[8];
#pragma unroll
  for (int i = 0; i < 8; ++i) {
    float a = fmaxf(sv[0][i], sv[0][i + 8]);
    if (blkmax == 2) a = fmaxf(a, fmaxf(sv[1][i], sv[1][i + 8]));
    red[i] = a;
  }
#pragma unroll
  for (int w = 4; w >= 1; w >>= 1)
#pragma unroll
    for (int i = 0; i < w; ++i) red[i] = fmaxf(red[i], red[i + w]);
  float tmax = red[0];
  tmax = fmaxf(tmax, __shfl_xor(tmax, 32));
  const float pmax = tmax * 0.125f;
  if (!__all(pmax - m <= 8.0f)) {
    const float mnew  = fmaxf(m, pmax);
    const float alpha = __builtin_amdgcn_exp2f((m - mnew) * LOG2E);
    m = mnew;
    l *= alpha;
#pragma unroll
    for (int db = 0; db < 2; ++db)
#pragma unroll
      for (int r = 0; r < 16; ++r) oacc[db][r] *= alpha;
  }
  const float km = 0.125f * LOG2E, kb = -m * LOG2E;
#pragma unroll
  for (int blk = 0; blk < 2; ++blk)
    if (blk < blkmax)
#pragma unroll
      for (int r = 0; r < 16; ++r)
        sv[blk][r] = __builtin_amdgcn_exp2f(__builtin_fmaf(sv[blk][r], km, kb));
  float sr[8];
#pragma unroll
  for (int i = 0; i < 8; ++i) {
    float a = sv[0][i] + sv[0][i + 8];
    if (blkmax == 2) a += sv[1][i] + sv[1][i + 8];
    sr[i] = a;
  }
#pragma unroll
  for (int w = 4; w >= 1; w >>= 1)
#pragma unroll
    for (int i = 0; i < w; ++i) sr[i] += sr[i + w];
  float sum = sr[0];
  sum += __shfl_xor(sum, 32);
  l += sum;

  // P redistribution (D-layout -> B-operand) + PV
#pragma unroll
  for (int blk = 0; blk < 2; ++blk)
    if (blk < blkmax) {
      uint32_t w[8], xw[8];
#pragma unroll
      for (int g = 0; g < 4; ++g) {
        w[2 * g]     = pk2(sv[blk][4 * g],     sv[blk][4 * g + 1]);
        w[2 * g + 1] = pk2(sv[blk][4 * g + 2], sv[blk][4 * g + 3]);
      }
#pragma unroll
      for (int i = 0; i < 8; ++i)
        xw[i] = (uint32_t)__shfl_xor((int)w[i], 32);
#pragma unroll
      for (int ks = 0; ks < 2; ++ks) {
        union { uint32_t u[4]; bf16x8 v; } pf;
        pf.u[0] = h ? xw[4 * ks + 2] : w[4 * ks];
        pf.u[1] = h ? xw[4 * ks + 3] : w[4 * ks + 1];
        pf.u[2] = h ? w[4 * ks + 2]  : xw[4 * ks];
        pf.u[3] = h ? w[4 * ks + 3]  : xw[4 * ks + 1];
        __builtin_amdgcn_s_setprio(1);
#pragma unroll
        for (int db = 0; db < 2; ++db)
          oacc[db] = __builtin_amdgcn_mfma_f32_32x32x16_bf16(
              vf[blk][ks][db], pf.v, oacc[db], 0, 0, 0);
        __builtin_amdgcn_s_setprio(0);
      }
    }
}

__global__ __launch_bounds__(128) void attn_fwd(
    const bf16* __restrict__ QKV, bf16* __restrict__ O)
{
  __shared__ bf16 Ks[2][64][64];   // K tiles [kv][d], rows XOR-swizzled
  __shared__ bf16 Vt[2][64][64];   // V^T tiles [d][kv], rows XOR-swizzled

  const int pr = blockIdx.x;       // pair index 0..15
  const int bh = blockIdx.y;
  const int bi = bh >> 4, hi = bh & 15;
  const int tid = threadIdx.x, wave = tid >> 6, lane = tid & 63;
  const int c = lane & 31, h = lane >> 5;

  const bf16* qptr = QKV + (size_t)bi * NSEQ * QKVS + hi * HD;
  const bf16* kptr = qptr + DM;
  const bf16* vptr = qptr + 2 * DM;

  // complementary strips (32 q-rows each)
  const int sA = 2 * pr + wave, sB = 63 - sA;
  const int q0A = sA * 32, q0B = sB * 32;

  bf16x8 qfA[4], qfB[4];
#pragma unroll
  for (int ks = 0; ks < 4; ++ks) {
    qfA[ks] = *(const bf16x8*)(qptr + (size_t)(q0A + c) * QKVS + ks * 16 + h * 8);
    qfB[ks] = *(const bf16x8*)(qptr + (size_t)(q0B + c) * QKVS + ks * 16 + h * 8);
  }

  f32x16 oaccA[2] = {}, oaccB[2] = {};
  float mA = -1e30f, lA = 0.f, mB = -1e30f, lB = 0.f;

  // K staging: 128 threads cover 16 rows x 8 chunks per pass, 4 passes
  const int srow = tid >> 3, sch = tid & 7;
  const int koff = (sch * 16) ^ ((srow & 7) << 4);   // (row+16p)&7 == row&7
  // V staging: thread covers 4 kv rows x 8 d cols (64x64 in one pass)
  const int kvg = (tid & 15) * 4, dg = (tid >> 4) * 8;

  bf16x8 kpre[4], vpre[4];      // prefetch regs (loaded t-1, published top of t+1)

  const int ntil = 32 - pr;     // tiles covering strip B (the larger)

  // prologue: tile0 -> LDS buf0 directly; tile1 -> regs
  {
#pragma unroll
    for (int p = 0; p < 4; ++p)
      kpre[p] = *(const bf16x8*)(kptr + (size_t)(srow + 16 * p) * QKVS + sch * 8);
#pragma unroll
    for (int i = 0; i < 4; ++i)
      vpre[i] = *(const bf16x8*)(vptr + (size_t)(kvg + i) * QKVS + dg);
#pragma unroll
    for (int p = 0; p < 4; ++p)
      *(bf16x8*)((char*)&Ks[0][srow + 16 * p][0] + koff) = kpre[p];
#pragma unroll
    for (int e = 0; e < 8; ++e) {
      const int d = dg + e;
      bf16x4 w; w[0] = vpre[0][e]; w[1] = vpre[1][e];
      w[2] = vpre[2][e]; w[3] = vpre[3][e];
      *(bf16x4*)((char*)&Vt[0][d][0] + ((2 * kvg) ^ ((d & 7) << 4))) = w;
    }
#pragma unroll
    for (int p = 0; p < 4; ++p)
      kpre[p] = *(const bf16x8*)(kptr + (size_t)(64 + srow + 16 * p) * QKVS + sch * 8);
#pragma unroll
    for (int i = 0; i < 4; ++i)
      vpre[i] = *(const bf16x8*)(vptr + (size_t)(64 + kvg + i) * QKVS + dg);
  }
  __syncthreads();

  for (int t = 0; t < ntil; ++t) {
    const int cur = t & 1;
    const int j0 = t * 64;

    // top: publish tile t+1 into the other buffer (its readers finished
    // before the barrier that ended iter t-1)
    if (t + 1 < ntil) {
      const int nb = cur ^ 1;
#pragma unroll
      for (int p = 0; p < 4; ++p)
        *(bf16x8*)((char*)&Ks[nb][srow + 16 * p][0] + koff) = kpre[p];
#pragma unroll
      for (int e = 0; e < 8; ++e) {
        const int d = dg + e;
        bf16x4 w; w[0] = vpre[0][e]; w[1] = vpre[1][e];
        w[2] = vpre[2][e]; w[3] = vpre[3][e];
        *(bf16x4*)((char*)&Vt[nb][d][0] + ((2 * kvg) ^ ((d & 7) << 4))) = w;
      }
    }
    // issue tile t+2 loads (land during next iteration's compute)
    if (t + 2 < ntil) {
      const int jn = j0 + 128;
#pragma unroll
      for (int p = 0; p < 4; ++p)
        kpre[p] = *(const bf16x8*)(kptr + (size_t)(jn + srow + 16 * p) * QKVS + sch * 8);
#pragma unroll
      for (int i = 0; i < 4; ++i)
        vpre[i] = *(const bf16x8*)(vptr + (size_t)(jn + kvg + i) * QKVS + dg);
    }

    // shared per-tile K/V fragments (strip-independent addresses)
    bf16x8 kf[2][4], vf[2][2][2];
#pragma unroll
    for (int blk = 0; blk < 2; ++blk) {
      const int krow = blk * 32 + c;
#pragma unroll
      for (int ks = 0; ks < 4; ++ks)
        kf[blk][ks] = *(const bf16x8*)((const char*)&Ks[cur][krow][0] +
                       ((ks * 32 + h * 16) ^ ((krow & 7) << 4)));
#pragma unroll
      for (int ks = 0; ks < 2; ++ks)
#pragma unroll
        for (int db = 0; db < 2; ++db) {
          const int vrow = db * 32 + c;
          vf[blk][ks][db] = *(const bf16x8*)((const char*)&Vt[cur][vrow][0] +
                             ((blk * 64 + ks * 32 + h * 16) ^ ((vrow & 7) << 4)));
        }
    }

    // strip B (large) on every staged tile; strip A while t <= pr
    strip_compute(kf, vf, qfB, oaccB, mB, lB, j0, q0B, c, h);
    if (j0 <= q0A + 31)
      strip_compute(kf, vf, qfA, oaccA, mA, lA, j0, q0A, c, h);

    __syncthreads();              // single barrier per tile
  }

  // epilogue: O[q][d] = oacc^T / l   (all lane-local)
#pragma unroll
  for (int sidx = 0; sidx < 2; ++sidx) {
    const f32x16* oacc = sidx ? oaccB : oaccA;
    const float linv = 1.f / (sidx ? lB : lA);
    const int q0 = sidx ? q0B : q0A;
    bf16* obase = O + (size_t)bi * NSEQ * DM + (size_t)hi * HD +
                  (size_t)(q0 + c) * DM;
#pragma unroll
    for (int db = 0; db < 2; ++db)
#pragma unroll
      for (int g = 0; g < 4; ++g) {
        bf16x4 ov;
#pragma unroll
        for (int j = 0; j < 4; ++j) ov[j] = (bf16)(oacc[db][4 * g + j] * linv);
        *(bf16x4*)(obase + db * 32 + 8 * g + 4 * h) = ov;
      }
  }
}

// ---------------- launch ----------------
extern "C" void kernel_launch(void* const* d_in, const int* in_sizes, int n_in,
                              void* d_out, int out_size, void* d_ws, size_t ws_size,
                              hipStream_t stream) {
  const void* x   = d_in[0];   // [2,2048,1024]
  const void* Wq  = d_in[1];   // [1024,1024]
  const void* Wkv = d_in[2];   // [1024,2048]
  const void* Wo  = d_in[3];   // [1024,1024]

  char* ws = (char*)d_ws;
  bf16* xb     = (bf16*)(ws + (4ull << 10));                    //   8 MiB
  bf16* WqkvT  = (bf16*)(ws + (4ull << 10) + (8ull  << 20));    //   6 MiB [3072][1024]
  bf16* WoT    = (bf16*)(ws + (4ull << 10) + (14ull << 20));    //   2 MiB [1024][1024]
  bf16* QKVb   = (bf16*)(ws + (4ull << 10) + (16ull << 20));    //  24 MiB [4096][3072]
  bf16* AOb    = xb;  // x dead after projection; reuse

  // fused prep: convert x + transpose all weights (inline dtype detect)
  prep<<<6144, 256, 0, stream>>>(x, Wq, Wkv, Wo, xb, WqkvT, WoT);

  // fused QKV projection: x @ [Wq | Wkv]
  gemm_bt<<<dim3(3072 / 128, 4096 / 128), 256, 0, stream>>>(
      xb, WqkvT, QKVb, 4096, 3072, 1024, nullptr);

  attn_fwd<<<dim3(16, 32), 128, 0, stream>>>(QKVb, AOb);

  gemm_bt<<<dim3(1024 / 128, 4096 / 128), 256, 0, stream>>>(
      AOb, WoT, d_out, 4096, 1024, 1024, (const uint32_t*)x);
}

// Round 20
// 127.119 us; speedup vs baseline: 1.0022x; 1.0022x over previous
//
#include <hip/hip_runtime.h>
#include <stdint.h>
#include <stddef.h>

// Attention_50886772523162: x[2,2048,1024] -> causal MHA (16 heads, hd=64) -> out
// dtype (fp32 vs bf16) detected inline (deterministic wave-local sample of x);
// compute bf16 MFMA, fp32 accum.
// Pipeline (4 launches): prep (convert x + transpose weights, fused) ->
//           QKV proj (one GEMM) -> flash attn (R12-verified, frozen) -> O proj.
// FINAL build = R16/R18 (verified twice: 127.3 / 127.4 us, replay-stable).
// BLACKLIST ledger:
//   - permlane32_swap: raw asm (R5) -> NaN; builtin (R17) -> wrong lanes.
//   - 4-buffer barrier-halving (R19): passes first launch, races under
//     graph replay (post-timing absmax 0.112) — unexplained, do not ship.
//   - K direct-from-global (R7), TLP schemes (R10/R11/R13), dual-strip ILP
//     (R14): all regressed.
// Kept wins: swapped-operand lane-local softmax (R3), write-at-top dbuf (R6),
//   complementary-strip balance (R9), shared K/V frags + tree reductions (R12),
//   fused prep + inline dtype detect (R15), 32x32x16 GEMM (R16).

typedef __bf16 bf16;
typedef __bf16 bf16x8 __attribute__((ext_vector_type(8)));
typedef __bf16 bf16x4 __attribute__((ext_vector_type(4)));
typedef __bf16 bf16x2 __attribute__((ext_vector_type(2)));
typedef float  f32x4  __attribute__((ext_vector_type(4)));
typedef float  f32x16 __attribute__((ext_vector_type(16)));

#define NSEQ 2048
#define DM   1024
#define HD   64
#define QKVS 3072          // fused QKV row stride
#define LOG2E 1.44269504f

#define GLD16(g, l) __builtin_amdgcn_global_load_lds(                         \
    (const __attribute__((address_space(1))) void*)(g),                       \
    (__attribute__((address_space(3))) void*)(l), 16, 0, 0)

// ---------------- inline dtype detection ----------------
static __device__ __forceinline__ int detect_bf16(const uint32_t* __restrict__ x) {
  const int lane = threadIdx.x & 63;
  int cc = 0;
#pragma unroll
  for (int k = 0; k < 16; ++k) {
    const uint32_t e = (x[lane * 16 + k] >> 7) & 0xFF;
    if (e >= 110 && e <= 132) cc++;
  }
#pragma unroll
  for (int off = 1; off < 64; off <<= 1) cc += __shfl_xor(cc, off);
  return cc > 512;   // of 1024 samples
}

// ---------------- fused prep: convert x + transpose(+convert) weights --------
__global__ __launch_bounds__(256) void prep(
    const void* __restrict__ x, const void* __restrict__ Wq,
    const void* __restrict__ Wkv, const void* __restrict__ Wo,
    bf16* __restrict__ xb, bf16* __restrict__ WqkvT, bf16* __restrict__ WoT)
{
  const int flag = detect_bf16((const uint32_t*)x);
  const int b = blockIdx.x, tid = threadIdx.x;

  if (b < 2048) {                      // ---- convert x ----
    const int i = (b * 256 + tid) * 8;
    if (flag) {
      *(bf16x8*)(xb + i) = *(const bf16x8*)((const bf16*)x + i);
    } else {
      const float* f = (const float*)x;
      bf16x8 v;
#pragma unroll
      for (int e = 0; e < 8; ++e) v[e] = (bf16)f[i + e];
      *(bf16x8*)(xb + i) = v;
    }
    return;                            // block-uniform exit (no barrier below)
  }

  // ---- weight transpose(+convert): in[K][N] -> out[N][K] ----
  __shared__ bf16 tile[32][33];
  const void* in;
  bf16* out;
  int K, N, idx;
  if (b < 3072)      { in = Wq;  out = WqkvT;               K = 1024; N = 1024; idx = b - 2048; }
  else if (b < 5120) { in = Wkv; out = WqkvT + 1024 * 1024; K = 1024; N = 2048; idx = b - 3072; }
  else               { in = Wo;  out = WoT;                 K = 1024; N = 1024; idx = b - 5120; }
  const int ntiles_n = N / 32;
  const int n0 = (idx % ntiles_n) * 32, k0 = (idx / ntiles_n) * 32;
  const int tx = tid & 31, ty = tid >> 5;    // 32 x 8

  if (flag) {
    const bf16* p = (const bf16*)in;
#pragma unroll
    for (int i = ty; i < 32; i += 8)
      tile[i][tx] = p[(size_t)(k0 + i) * N + n0 + tx];
  } else {
    const float* p = (const float*)in;
#pragma unroll
    for (int i = ty; i < 32; i += 8)
      tile[i][tx] = (bf16)p[(size_t)(k0 + i) * N + n0 + tx];
  }
  __syncthreads();
#pragma unroll
  for (int i = ty; i < 32; i += 8)
    out[(size_t)(n0 + i) * K + k0 + tx] = tile[tx][i];
}

// ---------------- GEMM: C[M][N] = A[M][K] * Bt[N][K]^T ----------------
// 128x128 tile, BK=64, 4 waves (2x2, each 64x64), mfma_f32_32x32x16_bf16.
__global__ __launch_bounds__(256) void gemm_bt(
    const bf16* __restrict__ A, const bf16* __restrict__ Bt,
    void* __restrict__ C, int M, int N, int K, const uint32_t* xdet)
{
  __shared__ bf16 As[128][64];
  __shared__ bf16 Bs[128][64];
  const int tid  = threadIdx.x;
  const int wave = tid >> 6, lane = tid & 63;
  const int c = lane & 31, h = lane >> 5;
  const int m0 = blockIdx.y * 128, n0 = blockIdx.x * 128;
  const int wr = (wave >> 1) * 64, wc = (wave & 1) * 64;
  const int lrow = lane >> 3;                    // row within 8-row chunk
  const int lcol = 8 * ((lane & 7) ^ lrow);      // pre-swizzled source col (elems)

  f32x16 acc[2][2] = {};

  for (int kt = 0; kt < K; kt += 64) {
    __syncthreads();                              // protect prev-iter reads
#pragma unroll
    for (int p = 0; p < 4; ++p) {
      const int chunk = wave * 4 + p;             // 8 rows per chunk
      const int r = chunk * 8 + lrow;
      GLD16(A  + (size_t)(m0 + r) * K + kt + lcol, &As[chunk * 8][0]);
      GLD16(Bt + (size_t)(n0 + r) * K + kt + lcol, &Bs[chunk * 8][0]);
    }
    __syncthreads();                              // vmcnt(0) drain + barrier
#pragma unroll
    for (int ks = 0; ks < 4; ++ks) {
      bf16x8 af[2], bfv[2];
#pragma unroll
      for (int mb = 0; mb < 2; ++mb) {
        const int ar = wr + mb * 32 + c;
        af[mb]  = *(const bf16x8*)((const char*)&As[ar][0] +
                   ((ks * 32 + h * 16) ^ ((ar & 7) << 4)));
        const int br = wc + mb * 32 + c;
        bfv[mb] = *(const bf16x8*)((const char*)&Bs[br][0] +
                   ((ks * 32 + h * 16) ^ ((br & 7) << 4)));
      }
#pragma unroll
      for (int mb = 0; mb < 2; ++mb)
#pragma unroll
        for (int nb = 0; nb < 2; ++nb)
          acc[mb][nb] = __builtin_amdgcn_mfma_f32_32x32x16_bf16(
              af[mb], bfv[nb], acc[mb][nb], 0, 0, 0);
    }
  }
  // D: col = n0+wc+nb*32+c ; row = m0+wr+mb*32 + (r&3)+8*(r>>2)+4*h
  const int as_bf16 = xdet ? detect_bf16(xdet) : 1;
  const int ccol = n0 + wc + c;
  if (as_bf16) {
    bf16* Cb = (bf16*)C;
#pragma unroll
    for (int mb = 0; mb < 2; ++mb)
#pragma unroll
      for (int nb = 0; nb < 2; ++nb)
#pragma unroll
        for (int r = 0; r < 16; ++r) {
          const int row = m0 + wr + mb * 32 + (r & 3) + 8 * (r >> 2) + 4 * h;
          Cb[(size_t)row * N + ccol + nb * 32] = (bf16)acc[mb][nb][r];
        }
  } else {
    float* Cf = (float*)C;
#pragma unroll
    for (int mb = 0; mb < 2; ++mb)
#pragma unroll
      for (int nb = 0; nb < 2; ++nb)
#pragma unroll
        for (int r = 0; r < 16; ++r) {
          const int row = m0 + wr + mb * 32 + (r & 3) + 8 * (r >> 2) + 4 * h;
          Cf[(size_t)row * N + ccol + nb * 32] = acc[mb][nb][r];
        }
  }
}

// ---------------- causal flash attention (R12-verified, frozen) ----------------
static __device__ inline uint32_t pk2(float a, float b) {
  bf16x2 t; t[0] = (bf16)a; t[1] = (bf16)b;
  return __builtin_bit_cast(uint32_t, t);
}

// One strip x one KV tile using pre-loaded K/V fragments.
static __device__ __forceinline__ void strip_compute(
    const bf16x8 (&kf)[2][4], const bf16x8 (&vf)[2][2][2],
    const bf16x8 (&qf)[4], f32x16 (&oacc)[2], float& m, float& l,
    const int j0, const int q0, const int c, const int h)
{
  const int qrow = q0 + c;
  const int blkmax = (j0 + 32 <= q0 + 31) ? 2 : 1;

  f32x16 sv[2];
  __builtin_amdgcn_s_setprio(1);
#pragma unroll
  for (int blk = 0; blk < 2; ++blk)
    if (blk < blkmax) {
      f32x16 a = {};
#pragma unroll
      for (int ks = 0; ks < 4; ++ks)
        a = __builtin_amdgcn_mfma_f32_32x32x16_bf16(kf[blk][ks], qf[ks], a, 0, 0, 0);
      sv[blk] = a;
    }
  __builtin_amdgcn_s_setprio(0);

  if (j0 + 63 > q0) {                       // causal mask (raw-S domain)
#pragma unroll
    for (int blk = 0; blk < 2; ++blk)
      if (blk < blkmax) {
        const int kvb = j0 + blk * 32 + 4 * h;
#pragma unroll
        for (int r = 0; r < 16; ++r) {
          const int kv = kvb + (r & 3) + 8 * (r >> 2);
          if (kv > qrow) sv[blk][r] = -4.0e8f;
        }
      }
  }

  // online softmax, lane-local; defer-max (T13, THR=8); tree reductions
  float red[8];
#pragma unroll
  for (int i = 0; i < 8; ++i) {
    float a = fmaxf(sv[0][i], sv[0][i + 8]);
    if (blkmax == 2) a = fmaxf(a, fmaxf(sv[1][i], sv[1][i + 8]));
    red[i] = a;
  }
#pragma unroll
  for (int w = 4; w >= 1; w >>= 1)
#pragma unroll
    for (int i = 0; i < w; ++i) red[i] = fmaxf(red[i], red[i + w]);
  float tmax = red[0];
  tmax = fmaxf(tmax, __shfl_xor(tmax, 32));
  const float pmax = tmax * 0.125f;
  if (!__all(pmax - m <= 8.0f)) {
    const float mnew  = fmaxf(m, pmax);
    const float alpha = __builtin_amdgcn_exp2f((m - mnew) * LOG2E);
    m = mnew;
    l *= alpha;
#pragma unroll
    for (int db = 0; db < 2; ++db)
#pragma unroll
      for (int r = 0; r < 16; ++r) oacc[db][r] *= alpha;
  }
  const float km = 0.125f * LOG2E, kb = -m * LOG2E;
#pragma unroll
  for (int blk = 0; blk < 2; ++blk)
    if (blk < blkmax)
#pragma unroll
      for (int r = 0; r < 16; ++r)
        sv[blk][r] = __builtin_amdgcn_exp2f(__builtin_fmaf(sv[blk][r], km, kb));
  float sr[8];
#pragma unroll
  for (int i = 0; i < 8; ++i) {
    float a = sv[0][i] + sv[0][i + 8];
    if (blkmax == 2) a += sv[1][i] + sv[1][i + 8];
    sr[i] = a;
  }
#pragma unroll
  for (int w = 4; w >= 1; w >>= 1)
#pragma unroll
    for (int i = 0; i < w; ++i) sr[i] += sr[i + w];
  float sum = sr[0];
  sum += __shfl_xor(sum, 32);
  l += sum;

  // P redistribution (D-layout -> B-operand) + PV
#pragma unroll
  for (int blk = 0; blk < 2; ++blk)
    if (blk < blkmax) {
      uint32_t w[8], xw[8];
#pragma unroll
      for (int g = 0; g < 4; ++g) {
        w[2 * g]     = pk2(sv[blk][4 * g],     sv[blk][4 * g + 1]);
        w[2 * g + 1] = pk2(sv[blk][4 * g + 2], sv[blk][4 * g + 3]);
      }
#pragma unroll
      for (int i = 0; i < 8; ++i)
        xw[i] = (uint32_t)__shfl_xor((int)w[i], 32);
#pragma unroll
      for (int ks = 0; ks < 2; ++ks) {
        union { uint32_t u[4]; bf16x8 v; } pf;
        pf.u[0] = h ? xw[4 * ks + 2] : w[4 * ks];
        pf.u[1] = h ? xw[4 * ks + 3] : w[4 * ks + 1];
        pf.u[2] = h ? w[4 * ks + 2]  : xw[4 * ks];
        pf.u[3] = h ? w[4 * ks + 3]  : xw[4 * ks + 1];
        __builtin_amdgcn_s_setprio(1);
#pragma unroll
        for (int db = 0; db < 2; ++db)
          oacc[db] = __builtin_amdgcn_mfma_f32_32x32x16_bf16(
              vf[blk][ks][db], pf.v, oacc[db], 0, 0, 0);
        __builtin_amdgcn_s_setprio(0);
      }
    }
}

__global__ __launch_bounds__(128) void attn_fwd(
    const bf16* __restrict__ QKV, bf16* __restrict__ O)
{
  __shared__ bf16 Ks[2][64][64];   // K tiles [kv][d], rows XOR-swizzled
  __shared__ bf16 Vt[2][64][64];   // V^T tiles [d][kv], rows XOR-swizzled

  const int pr = blockIdx.x;       // pair index 0..15
  const int bh = blockIdx.y;
  const int bi = bh >> 4, hi = bh & 15;
  const int tid = threadIdx.x, wave = tid >> 6, lane = tid & 63;
  const int c = lane & 31, h = lane >> 5;

  const bf16* qptr = QKV + (size_t)bi * NSEQ * QKVS + hi * HD;
  const bf16* kptr = qptr + DM;
  const bf16* vptr = qptr + 2 * DM;

  // complementary strips (32 q-rows each)
  const int sA = 2 * pr + wave, sB = 63 - sA;
  const int q0A = sA * 32, q0B = sB * 32;

  bf16x8 qfA[4], qfB[4];
#pragma unroll
  for (int ks = 0; ks < 4; ++ks) {
    qfA[ks] = *(const bf16x8*)(qptr + (size_t)(q0A + c) * QKVS + ks * 16 + h * 8);
    qfB[ks] = *(const bf16x8*)(qptr + (size_t)(q0B + c) * QKVS + ks * 16 + h * 8);
  }

  f32x16 oaccA[2] = {}, oaccB[2] = {};
  float mA = -1e30f, lA = 0.f, mB = -1e30f, lB = 0.f;

  // K staging: 128 threads cover 16 rows x 8 chunks per pass, 4 passes
  const int srow = tid >> 3, sch = tid & 7;
  const int koff = (sch * 16) ^ ((srow & 7) << 4);   // (row+16p)&7 == row&7
  // V staging: thread covers 4 kv rows x 8 d cols (64x64 in one pass)
  const int kvg = (tid & 15) * 4, dg = (tid >> 4) * 8;

  bf16x8 kpre[4], vpre[4];      // prefetch regs (loaded t-1, published top of t+1)

  const int ntil = 32 - pr;     // tiles covering strip B (the larger)

  // prologue: tile0 -> LDS buf0 directly; tile1 -> regs
  {
#pragma unroll
    for (int p = 0; p < 4; ++p)
      kpre[p] = *(const bf16x8*)(kptr + (size_t)(srow + 16 * p) * QKVS + sch * 8);
#pragma unroll
    for (int i = 0; i < 4; ++i)
      vpre[i] = *(const bf16x8*)(vptr + (size_t)(kvg + i) * QKVS + dg);
#pragma unroll
    for (int p = 0; p < 4; ++p)
      *(bf16x8*)((char*)&Ks[0][srow + 16 * p][0] + koff) = kpre[p];
#pragma unroll
    for (int e = 0; e < 8; ++e) {
      const int d = dg + e;
      bf16x4 w; w[0] = vpre[0][e]; w[1] = vpre[1][e];
      w[2] = vpre[2][e]; w[3] = vpre[3][e];
      *(bf16x4*)((char*)&Vt[0][d][0] + ((2 * kvg) ^ ((d & 7) << 4))) = w;
    }
#pragma unroll
    for (int p = 0; p < 4; ++p)
      kpre[p] = *(const bf16x8*)(kptr + (size_t)(64 + srow + 16 * p) * QKVS + sch * 8);
#pragma unroll
    for (int i = 0; i < 4; ++i)
      vpre[i] = *(const bf16x8*)(vptr + (size_t)(64 + kvg + i) * QKVS + dg);
  }
  __syncthreads();

  for (int t = 0; t < ntil; ++t) {
    const int cur = t & 1;
    const int j0 = t * 64;

    // top: publish tile t+1 into the other buffer (its readers finished
    // before the barrier that ended iter t-1)
    if (t + 1 < ntil) {
      const int nb = cur ^ 1;
#pragma unroll
      for (int p = 0; p < 4; ++p)
        *(bf16x8*)((char*)&Ks[nb][srow + 16 * p][0] + koff) = kpre[p];
#pragma unroll
      for (int e = 0; e < 8; ++e) {
        const int d = dg + e;
        bf16x4 w; w[0] = vpre[0][e]; w[1] = vpre[1][e];
        w[2] = vpre[2][e]; w[3] = vpre[3][e];
        *(bf16x4*)((char*)&Vt[nb][d][0] + ((2 * kvg) ^ ((d & 7) << 4))) = w;
      }
    }
    // issue tile t+2 loads (land during next iteration's compute)
    if (t + 2 < ntil) {
      const int jn = j0 + 128;
#pragma unroll
      for (int p = 0; p < 4; ++p)
        kpre[p] = *(const bf16x8*)(kptr + (size_t)(jn + srow + 16 * p) * QKVS + sch * 8);
#pragma unroll
      for (int i = 0; i < 4; ++i)
        vpre[i] = *(const bf16x8*)(vptr + (size_t)(jn + kvg + i) * QKVS + dg);
    }

    // shared per-tile K/V fragments (strip-independent addresses)
    bf16x8 kf[2][4], vf[2][2][2];
#pragma unroll
    for (int blk = 0; blk < 2; ++blk) {
      const int krow = blk * 32 + c;
#pragma unroll
      for (int ks = 0; ks < 4; ++ks)
        kf[blk][ks] = *(const bf16x8*)((const char*)&Ks[cur][krow][0] +
                       ((ks * 32 + h * 16) ^ ((krow & 7) << 4)));
#pragma unroll
      for (int ks = 0; ks < 2; ++ks)
#pragma unroll
        for (int db = 0; db < 2; ++db) {
          const int vrow = db * 32 + c;
          vf[blk][ks][db] = *(const bf16x8*)((const char*)&Vt[cur][vrow][0] +
                             ((blk * 64 + ks * 32 + h * 16) ^ ((vrow & 7) << 4)));
        }
    }

    // strip B (large) on every staged tile; strip A while t <= pr
    strip_compute(kf, vf, qfB, oaccB, mB, lB, j0, q0B, c, h);
    if (j0 <= q0A + 31)
      strip_compute(kf, vf, qfA, oaccA, mA, lA, j0, q0A, c, h);

    __syncthreads();              // single barrier per tile
  }

  // epilogue: O[q][d] = oacc^T / l   (all lane-local)
#pragma unroll
  for (int sidx = 0; sidx < 2; ++sidx) {
    const f32x16* oacc = sidx ? oaccB : oaccA;
    const float linv = 1.f / (sidx ? lB : lA);
    const int q0 = sidx ? q0B : q0A;
    bf16* obase = O + (size_t)bi * NSEQ * DM + (size_t)hi * HD +
                  (size_t)(q0 + c) * DM;
#pragma unroll
    for (int db = 0; db < 2; ++db)
#pragma unroll
      for (int g = 0; g < 4; ++g) {
        bf16x4 ov;
#pragma unroll
        for (int j = 0; j < 4; ++j) ov[j] = (bf16)(oacc[db][4 * g + j] * linv);
        *(bf16x4*)(obase + db * 32 + 8 * g + 4 * h) = ov;
      }
  }
}

// ---------------- launch ----------------
extern "C" void kernel_launch(void* const* d_in, const int* in_sizes, int n_in,
                              void* d_out, int out_size, void* d_ws, size_t ws_size,
                              hipStream_t stream) {
  const void* x   = d_in[0];   // [2,2048,1024]
  const void* Wq  = d_in[1];   // [1024,1024]
  const void* Wkv = d_in[2];   // [1024,2048]
  const void* Wo  = d_in[3];   // [1024,1024]

  char* ws = (char*)d_ws;
  bf16* xb     = (bf16*)(ws + (4ull << 10));                    //   8 MiB
  bf16* WqkvT  = (bf16*)(ws + (4ull << 10) + (8ull  << 20));    //   6 MiB [3072][1024]
  bf16* WoT    = (bf16*)(ws + (4ull << 10) + (14ull << 20));    //   2 MiB [1024][1024]
  bf16* QKVb   = (bf16*)(ws + (4ull << 10) + (16ull << 20));    //  24 MiB [4096][3072]
  bf16* AOb    = xb;  // x dead after projection; reuse

  // fused prep: convert x + transpose all weights (inline dtype detect)
  prep<<<6144, 256, 0, stream>>>(x, Wq, Wkv, Wo, xb, WqkvT, WoT);

  // fused QKV projection: x @ [Wq | Wkv]
  gemm_bt<<<dim3(3072 / 128, 4096 / 128), 256, 0, stream>>>(
      xb, WqkvT, QKVb, 4096, 3072, 1024, nullptr);

  attn_fwd<<<dim3(16, 32), 128, 0, stream>>>(QKVb, AOb);

  gemm_bt<<<dim3(1024 / 128, 4096 / 128), 256, 0, stream>>>(
      AOb, WoT, d_out, 4096, 1024, 1024, (const uint32_t*)x);
}